// Round 1
// baseline (961.231 us; speedup 1.0000x reference)
//
#include <hip/hip_runtime.h>
#include <hip/hip_bf16.h>

#define N_NODES 200000
#define E1 1600000
#define N1P 100000
#define E2P 100000
#define N2P 50000
#define BGR 1000
#define C1 32
#define C2 64
#define HIDN 25
#define NCLS 10

__device__ __forceinline__ float elu1(float v) {
    return v > 0.f ? v : expm1f(v);
}

// ---------------- conv1: per-edge MLP(2->25->32), msg = x[src]*w, atomic agg to dst
// 8 lanes per edge; lane l handles o = k*8 + l, k=0..3 (32B contiguous atomic segments)
__global__ __launch_bounds__(256) void conv1_kernel(
    const float* __restrict__ x, const float* __restrict__ ea,
    const int* __restrict__ ei,
    const float* __restrict__ w1, const float* __restrict__ b1,
    const float* __restrict__ w2, const float* __restrict__ b2,
    float* __restrict__ agg1)
{
    int tid = threadIdx.x;
    int lane = tid & 63;
    int wib = tid >> 6;
    int grp = lane >> 3;           // 8 edges per wave
    int l = lane & 7;
    int e = blockIdx.x * 32 + wib * 8 + grp;
    if (e >= E1) return;

    float a0 = ea[2 * e], a1 = ea[2 * e + 1];
    int src = ei[e], dst = ei[E1 + e];

    float hid[HIDN];
#pragma unroll
    for (int h = 0; h < HIDN; ++h) {
        float v = fmaf(a0, w1[h], fmaf(a1, w1[HIDN + h], b1[h]));
        hid[h] = v > 0.f ? v : 0.f;
    }
    float xs = x[src];

    float acc[4];
#pragma unroll
    for (int k = 0; k < 4; ++k) acc[k] = b2[k * 8 + l];
#pragma unroll
    for (int h = 0; h < HIDN; ++h) {
        float hv = hid[h];
#pragma unroll
        for (int k = 0; k < 4; ++k)
            acc[k] = fmaf(hv, w2[h * C1 + k * 8 + l], acc[k]);
    }
    float* dp = agg1 + (size_t)dst * C1;
#pragma unroll
    for (int k = 0; k < 4; ++k)
        atomicAdd(dp + k * 8 + l, xs * acc[k]);
}

// ---------------- finish conv1 (root+bias+elu) and pool1 (pairwise max) + pos mean
__global__ __launch_bounds__(256) void pool1_kernel(
    const float* __restrict__ agg1, const float* __restrict__ x,
    const float* __restrict__ root1, const float* __restrict__ bias1,
    const float* __restrict__ pos, float* __restrict__ x1, float* __restrict__ pos1)
{
    int t = blockIdx.x * blockDim.x + threadIdx.x;
    if (t >= N1P * C1) return;
    int j = t >> 5, o = t & 31;
    int na = 2 * j, nb = 2 * j + 1;
    float r = root1[o], bo = bias1[o];
    float ha = elu1(agg1[(size_t)na * C1 + o] + x[na] * r + bo);
    float hb = elu1(agg1[(size_t)nb * C1 + o] + x[nb] * r + bo);
    x1[t] = fmaxf(ha, hb);
    if (o < 2) pos1[j * 2 + o] = 0.5f * (pos[na * 2 + o] + pos[nb * 2 + o]);
}

// ---------------- global max|cart| over pooled edges
__global__ __launch_bounds__(256) void maxabs_kernel(
    const int* __restrict__ ei2, const float* __restrict__ pos1,
    unsigned int* __restrict__ maxbits)
{
    int e = blockIdx.x * blockDim.x + threadIdx.x;
    float m = 0.f;
    if (e < E2P) {
        int s = ei2[e], d = ei2[E2P + e];
        float c0 = pos1[2 * s] - pos1[2 * d];
        float c1 = pos1[2 * s + 1] - pos1[2 * d + 1];
        m = fmaxf(fabsf(c0), fabsf(c1));
    }
#pragma unroll
    for (int off = 32; off; off >>= 1)
        m = fmaxf(m, __shfl_down(m, off));
    if ((threadIdx.x & 63) == 0)
        atomicMax(maxbits, __float_as_uint(m));
}

// ---------------- conv2: per-edge MLP(2->25->2048) bilinear with x1[src][32] -> msg[64]
// thread per (edge, o-half); all W2 reads wave-uniform -> scalar path
__global__ __launch_bounds__(256) void conv2_kernel(
    const int* __restrict__ ei2, const float* __restrict__ pos1,
    const float* __restrict__ x1,
    const float* __restrict__ w1, const float* __restrict__ b1,
    const float* __restrict__ w2, const float* __restrict__ b2,
    const unsigned int* __restrict__ maxbits,
    float* __restrict__ agg2)
{
    int e = blockIdx.x * 256 + threadIdx.x;
    if (e >= E2P) return;
    int ob = blockIdx.y * 32;   // o half base, wave-uniform

    float inv = 0.5f / __uint_as_float(*maxbits);
    int s = ei2[e], d = ei2[E2P + e];
    float a0 = (pos1[2 * s] - pos1[2 * d]) * inv + 0.5f;
    float a1 = (pos1[2 * s + 1] - pos1[2 * d + 1]) * inv + 0.5f;

    float hid[HIDN];
#pragma unroll
    for (int h = 0; h < HIDN; ++h) {
        float v = fmaf(a0, w1[h], fmaf(a1, w1[HIDN + h], b1[h]));
        hid[h] = v > 0.f ? v : 0.f;
    }
    float xs[C1];
#pragma unroll
    for (int i = 0; i < C1; ++i) xs[i] = x1[(size_t)s * C1 + i];

    float msg[32];
#pragma unroll
    for (int oo = 0; oo < 32; ++oo) msg[oo] = 0.f;

    // n2_b2 contribution: msg[oo] += xs[i] * b2[i*64 + ob + oo]
#pragma unroll 1
    for (int i = 0; i < C1; ++i) {
        float xv = xs[i];
#pragma unroll
        for (int oo = 0; oo < 32; ++oo)
            msg[oo] = fmaf(xv, b2[i * C2 + ob + oo], msg[oo]);
    }

#pragma unroll 1
    for (int h = 0; h < HIDN; ++h) {
        float hv = hid[h];
        const float* w2h = w2 + (size_t)h * (C1 * C2) + ob;
#pragma unroll
        for (int i = 0; i < C1; ++i) {
            float c = hv * xs[i];
#pragma unroll
            for (int oo = 0; oo < 32; ++oo)
                msg[oo] = fmaf(c, w2h[i * C2 + oo], msg[oo]);
        }
    }
    float* dp = agg2 + (size_t)d * C2 + ob;
#pragma unroll
    for (int oo = 0; oo < 32; ++oo)
        atomicAdd(dp + oo, msg[oo]);
}

// ---------------- finish conv2 (root2+bias2+elu), pool2 (pairwise max), per-graph mean
__global__ __launch_bounds__(256) void pool2_kernel(
    const float* __restrict__ agg2, const float* __restrict__ x1,
    const float* __restrict__ root2, const float* __restrict__ bias2,
    float* __restrict__ g)
{
    int b = blockIdx.x;
    int w = threadIdx.x >> 6, o = threadIdx.x & 63;
    __shared__ float part[4][C2];
    float sum = 0.f;
    for (int jj = w; jj < 50; jj += 4) {
        int j = b * 50 + jj;
        float hv[2];
#pragma unroll
        for (int t = 0; t < 2; ++t) {
            int n = 2 * j + t;
            float a = agg2[(size_t)n * C2 + o] + bias2[o];
#pragma unroll
            for (int i = 0; i < C1; ++i)
                a = fmaf(x1[(size_t)n * C1 + i], root2[i * C2 + o], a);
            hv[t] = elu1(a);
        }
        sum += fmaxf(hv[0], hv[1]);
    }
    part[w][o] = sum;
    __syncthreads();
    if (w == 0) {
        float s2 = part[0][o] + part[1][o] + part[2][o] + part[3][o];
        g[b * C2 + o] = s2 * (1.f / 50.f);
    }
}

// ---------------- FC head: g[64] -> elu(fc1) [128] -> fc2 [10] -> log_softmax
__global__ __launch_bounds__(128) void head_kernel(
    const float* __restrict__ g,
    const float* __restrict__ fc1w, const float* __restrict__ fc1b,
    const float* __restrict__ fc2w, const float* __restrict__ fc2b,
    float* __restrict__ out)
{
    int b = blockIdx.x;
    int t = threadIdx.x;
    __shared__ float gs[C2];
    __shared__ float zs[128];
    __shared__ float ls[NCLS];
    if (t < C2) gs[t] = g[b * C2 + t];
    __syncthreads();
    float z = fc1b[t];
#pragma unroll
    for (int i = 0; i < C2; ++i) z = fmaf(gs[i], fc1w[i * 128 + t], z);
    zs[t] = elu1(z);
    __syncthreads();
    if (t < NCLS) {
        float l = fc2b[t];
#pragma unroll
        for (int k = 0; k < 128; ++k) l = fmaf(zs[k], fc2w[k * NCLS + t], l);
        ls[t] = l;
    }
    __syncthreads();
    if (t < NCLS) {
        float mx = ls[0];
#pragma unroll
        for (int c = 1; c < NCLS; ++c) mx = fmaxf(mx, ls[c]);
        float se = 0.f;
#pragma unroll
        for (int c = 0; c < NCLS; ++c) se += expf(ls[c] - mx);
        out[b * NCLS + t] = ls[t] - mx - logf(se);
    }
}

extern "C" void kernel_launch(void* const* d_in, const int* in_sizes, int n_in,
                              void* d_out, int out_size, void* d_ws, size_t ws_size,
                              hipStream_t stream)
{
    const float* x    = (const float*)d_in[0];
    const float* pos  = (const float*)d_in[1];
    const int*   ei   = (const int*)d_in[2];
    const float* ea   = (const float*)d_in[3];
    const int*   ei2  = (const int*)d_in[6];
    const float* n1w1 = (const float*)d_in[8];
    const float* n1b1 = (const float*)d_in[9];
    const float* n1w2 = (const float*)d_in[10];
    const float* n1b2 = (const float*)d_in[11];
    const float* root1= (const float*)d_in[12];
    const float* bias1= (const float*)d_in[13];
    const float* n2w1 = (const float*)d_in[14];
    const float* n2b1 = (const float*)d_in[15];
    const float* n2w2 = (const float*)d_in[16];
    const float* n2b2 = (const float*)d_in[17];
    const float* root2= (const float*)d_in[18];
    const float* bias2= (const float*)d_in[19];
    const float* fc1w = (const float*)d_in[20];
    const float* fc1b = (const float*)d_in[21];
    const float* fc2w = (const float*)d_in[22];
    const float* fc2b = (const float*)d_in[23];
    float* out = (float*)d_out;

    float* agg1 = (float*)d_ws;                               // N*32
    float* x1   = agg1 + (size_t)N_NODES * C1;                // N1*32
    float* pos1 = x1 + (size_t)N1P * C1;                      // N1*2
    unsigned int* maxbits = (unsigned int*)(pos1 + (size_t)N1P * 2);
    float* agg2 = (float*)(maxbits + 64);                     // N1*64
    float* g    = agg2 + (size_t)N1P * C2;                    // B*64

    hipMemsetAsync(agg1, 0, (size_t)N_NODES * C1 * sizeof(float), stream);
    hipMemsetAsync(agg2, 0, (size_t)N1P * C2 * sizeof(float), stream);
    hipMemsetAsync(maxbits, 0, 64 * sizeof(unsigned int), stream);

    conv1_kernel<<<E1 / 32, 256, 0, stream>>>(x, ea, ei, n1w1, n1b1, n1w2, n1b2, agg1);
    pool1_kernel<<<(N1P * C1 + 255) / 256, 256, 0, stream>>>(agg1, x, root1, bias1, pos, x1, pos1);
    maxabs_kernel<<<(E2P + 255) / 256, 256, 0, stream>>>(ei2, pos1, maxbits);
    conv2_kernel<<<dim3((E2P + 255) / 256, 2), 256, 0, stream>>>(ei2, pos1, x1, n2w1, n2b1, n2w2, n2b2, maxbits, agg2);
    pool2_kernel<<<BGR, 256, 0, stream>>>(agg2, x1, root2, bias2, g);
    head_kernel<<<BGR, 128, 0, stream>>>(g, fc1w, fc1b, fc2w, fc2b, out);
}